// Round 1
// baseline (43.232 us; speedup 1.0000x reference)
//
#include <hip/hip_runtime.h>

#define HW    65536
#define Wd    256
#define Hd    256
#define Bn    4
#define Mn    100
#define Dn    128

// ---------------- K1: per-cell variance over D=128 (one 32-lane group per row)
__global__ __launch_bounds__(256) void var_kernel(const float* __restrict__ atten,
                                                  float* __restrict__ v) {
    int t = blockIdx.x * 256 + threadIdx.x;
    int row = t >> 5;          // 262144 rows
    int lane = t & 31;
    const float4* p = reinterpret_cast<const float4*>(atten + (size_t)row * Dn) + lane;
    float4 x = *p;
    float s = x.x + x.y + x.z + x.w;
    float q = x.x * x.x + x.y * x.y + x.z * x.z + x.w * x.w;
    #pragma unroll
    for (int m = 16; m; m >>= 1) {
        s += __shfl_xor(s, m);
        q += __shfl_xor(q, m);
    }
    if (lane == 0)
        v[row] = (q - s * s * (1.0f / 128.0f)) * (1.0f / 127.0f);
}

// ---------------- K2: box geometry (corners/edges/prune radius) + zero accumulators
__global__ __launch_bounds__(256) void geom_kernel(const float* __restrict__ boxes,
                                                   float* __restrict__ bws,
                                                   float* __restrict__ gsum,
                                                   float* __restrict__ gcnt) {
    int t = blockIdx.x * 256 + threadIdx.x;
    if (t < Bn * Mn) { gsum[t] = 0.0f; gcnt[t] = 0.0f; }
    if (t >= Bn * Mn) return;

    const float* bx = boxes + t * 7;
    float cx = bx[0], cy = bx[1];
    float l = bx[3], w = bx[4];
    float yaw = bx[6];

    const float DIMS0 = 51.2f + 51.2f;          // matches np float32 51.2f-(-51.2f)
    const float cellw = DIMS0 / 256.0f;         // exact scale by 2^-8
    float rl = fminf(fmaxf(cellw / l, 1.0f), 6.0f);
    float rw = fminf(fmaxf(cellw / w, 1.0f), 6.0f);
    float el = __fmul_rn(l, rl);
    float ew = __fmul_rn(w, rw);
    float c = cosf(yaw), s = sinf(yaw);

    const float nx[4] = {-0.5f, -0.5f, 0.5f, 0.5f};
    const float ny[4] = {-0.5f, 0.5f, 0.5f, -0.5f};
    float px[4], py[4];
    #pragma unroll
    for (int k = 0; k < 4; k++) {
        float ox = __fmul_rn(el, nx[k]);
        float oy = __fmul_rn(ew, ny[k]);
        float rx = __fadd_rn(__fmul_rn(ox, c), __fmul_rn(oy, s));
        float ry = __fadd_rn(__fmul_rn(-ox, s), __fmul_rn(oy, c));
        px[k] = __fadd_rn(rx, cx);
        py[k] = __fadd_rn(ry, cy);
    }
    float* o = bws + t * 20;
    #pragma unroll
    for (int k = 0; k < 4; k++) { o[k * 2] = px[k]; o[k * 2 + 1] = py[k]; }
    #pragma unroll
    for (int k = 0; k < 4; k++) {
        o[8 + k * 2]     = __fsub_rn(px[(k + 1) & 3], px[k]);
        o[8 + k * 2 + 1] = __fsub_rn(py[(k + 1) & 3], py[k]);
    }
    o[16] = cy;
    o[17] = 0.5f * sqrtf(el * el + ew * ew) + 0.01f;  // conservative prune radius
    o[18] = 0.0f; o[19] = 0.0f;
}

// ---------------- K3: per-cell parity-scan flag + segment accumulate
__global__ __launch_bounds__(256) void flag_kernel(const float* __restrict__ bws,
                                                   const float* __restrict__ v,
                                                   float* __restrict__ gsum,
                                                   float* __restrict__ gcnt) {
    __shared__ float sbox[Mn * 20];
    __shared__ float ssum[Mn];
    __shared__ float scnt[Mn];
    int b = blockIdx.x >> 8;       // 4 scenes x 256 rows
    int y = blockIdx.x & 255;
    int x = threadIdx.x;

    for (int i = threadIdx.x; i < Mn * 20; i += 256)
        sbox[i] = bws[b * Mn * 20 + i];
    if (threadIdx.x < Mn) { ssum[threadIdx.x] = 0.0f; scnt[threadIdx.x] = 0.0f; }
    __syncthreads();

    const float DIMS0 = 51.2f + 51.2f;
    float gx = __fadd_rn(__fmul_rn((x + 0.5f) * (1.0f / 256.0f), DIMS0), -51.2f);
    float gy = __fadd_rn(__fmul_rn((y + 0.5f) * (1.0f / 256.0f), DIMS0), -51.2f);

    int flag = -1;
    for (int m = 0; m < Mn; m++) {
        const float* o = &sbox[m * 20];
        if (fabsf(gy - o[16]) > o[17]) continue;   // uniform y-band prune
        bool ge = true, le = true;
        #pragma unroll
        for (int k = 0; k < 4; k++) {
            float dx = __fsub_rn(gx, o[k * 2]);
            float dy = __fsub_rn(gy, o[k * 2 + 1]);
            float cr = __fsub_rn(__fmul_rn(o[8 + k * 2], dy),
                                 __fmul_rn(o[8 + k * 2 + 1], dx));
            ge = ge && (cr >= 0.0f);
            le = le && (cr <= 0.0f);
        }
        if (ge || le) flag = (flag == -1) ? m : -1;
    }

    if (flag >= 0) {
        float vv = v[b * HW + y * 256 + x];
        atomicAdd(&ssum[flag], vv);
        atomicAdd(&scnt[flag], 1.0f);
    }
    __syncthreads();
    if (threadIdx.x < Mn && scnt[threadIdx.x] > 0.0f) {
        atomicAdd(&gsum[b * Mn + threadIdx.x], ssum[threadIdx.x]);
        atomicAdd(&gcnt[b * Mn + threadIdx.x], scnt[threadIdx.x]);
    }
}

// ---------------- K4: finalize scalar loss
__global__ __launch_bounds__(512) void final_kernel(const float* __restrict__ gsum,
                                                    const float* __restrict__ gcnt,
                                                    float* __restrict__ out) {
    __shared__ float sl[8], sn[8];
    int t = threadIdx.x;
    float loss = 0.0f, num = 0.0f;
    if (t < Bn * Mn) {
        float c = gcnt[t];
        if (c > 0.0f) {
            loss = -(gsum[t] / fmaxf(c, 1.0f));
            num = 1.0f;
        }
    }
    #pragma unroll
    for (int m = 32; m; m >>= 1) {
        loss += __shfl_xor(loss, m);
        num  += __shfl_xor(num, m);
    }
    if ((t & 63) == 0) { sl[t >> 6] = loss; sn[t >> 6] = num; }
    __syncthreads();
    if (t == 0) {
        float L = 0.0f, N = 0.0f;
        #pragma unroll
        for (int i = 0; i < 8; i++) { L += sl[i]; N += sn[i]; }
        out[0] = L / fmaxf(N, 1.0f);
    }
}

extern "C" void kernel_launch(void* const* d_in, const int* in_sizes, int n_in,
                              void* d_out, int out_size, void* d_ws, size_t ws_size,
                              hipStream_t stream) {
    const float* atten = (const float*)d_in[0];
    const float* boxes = (const float*)d_in[1];
    float* out = (float*)d_out;

    float* v    = (float*)d_ws;            // B*HW floats         (1 MB)
    float* bws  = v + (size_t)Bn * HW;     // B*M*20 floats       (32 KB)
    float* gsum = bws + Bn * Mn * 20;      // B*M floats
    float* gcnt = gsum + Bn * Mn;          // B*M floats

    // K1: 262144 rows * 32 lanes / 256 threads = 32768 blocks
    var_kernel<<<32768, 256, 0, stream>>>(atten, v);
    geom_kernel<<<2, 256, 0, stream>>>(boxes, bws, gsum, gcnt);
    flag_kernel<<<Bn * Hd, 256, 0, stream>>>(bws, v, gsum, gcnt);
    final_kernel<<<1, 512, 0, stream>>>(gsum, gcnt, out);
}